// Round 1
// baseline (280.340 us; speedup 1.0000x reference)
//
#include <hip/hip_runtime.h>

#define DIN 48
#define DOUT 16
#define DC 32  // combined output dims: [mu(16) | logstd(16)]

__global__ void k_init_deg(float* __restrict__ deg, int n) {
    int i = blockIdx.x * blockDim.x + threadIdx.x;
    if (i < n) deg[i] = 1.0f;
}

__global__ void k_count(const int* __restrict__ dst, float* __restrict__ deg, int e_cnt) {
    int e = blockIdx.x * blockDim.x + threadIdx.x;
    if (e < e_cnt) unsafeAtomicAdd(&deg[dst[e]], 1.0f);
}

// Per node: proj = x @ [Wmu|Wls]; dinv = rsqrt(deg) (stored in-place);
// out = bias + dinv^2 * proj   (self-loop term, full overwrite of d_out)
__global__ void k_proj(const float* __restrict__ x,
                       const float* __restrict__ Wmu, const float* __restrict__ bmu,
                       const float* __restrict__ Wls, const float* __restrict__ bls,
                       float* __restrict__ deg_dinv, float* __restrict__ proj,
                       float* __restrict__ out, int n) {
    __shared__ float Ws[DIN * DC];
    __shared__ float bs[DC];
    int t = threadIdx.x;
    for (int idx = t; idx < DIN * DC; idx += blockDim.x) {
        int k = idx >> 5, j = idx & 31;
        Ws[idx] = (j < DOUT) ? Wmu[k * DOUT + j] : Wls[k * DOUT + (j - DOUT)];
    }
    if (t < DC) bs[t] = (t < DOUT) ? bmu[t] : bls[t - DOUT];
    __syncthreads();

    int i = blockIdx.x * blockDim.x + t;
    if (i >= n) return;

    float xr[DIN];
    const float4* xp = reinterpret_cast<const float4*>(x + (size_t)i * DIN);
#pragma unroll
    for (int q = 0; q < DIN / 4; ++q) {
        float4 v = xp[q];
        xr[4 * q + 0] = v.x; xr[4 * q + 1] = v.y;
        xr[4 * q + 2] = v.z; xr[4 * q + 3] = v.w;
    }

    float acc[DC];
#pragma unroll
    for (int j = 0; j < DC; ++j) acc[j] = 0.0f;
#pragma unroll 4
    for (int k = 0; k < DIN; ++k) {
        float xv = xr[k];
#pragma unroll
        for (int j = 0; j < DC; ++j) acc[j] += xv * Ws[k * DC + j];
    }

    float dv = rsqrtf(deg_dinv[i]);
    deg_dinv[i] = dv;          // overwrite deg with dinv for the scatter kernel
    float d2 = dv * dv;

    float4* pp = reinterpret_cast<float4*>(proj + (size_t)i * DC);
#pragma unroll
    for (int q = 0; q < DC / 4; ++q) {
        float4 v;
        v.x = acc[4 * q + 0]; v.y = acc[4 * q + 1];
        v.z = acc[4 * q + 2]; v.w = acc[4 * q + 3];
        pp[q] = v;
    }

    float* omu = out + (size_t)i * DOUT;
    float* ols = out + (size_t)n * DOUT + (size_t)i * DOUT;
#pragma unroll
    for (int j = 0; j < DOUT; ++j) omu[j] = bs[j] + d2 * acc[j];
#pragma unroll
    for (int j = 0; j < DOUT; ++j) ols[j] = bs[DOUT + j] + d2 * acc[DOUT + j];
}

// One lane per (edge, combined-dim). 32 lanes share an edge.
__global__ void k_scatter(const int* __restrict__ src, const int* __restrict__ dst,
                          const float* __restrict__ dinv, const float* __restrict__ proj,
                          float* __restrict__ out, int e_cnt, int n) {
    long long gid = (long long)blockIdx.x * blockDim.x + threadIdx.x;
    int e = (int)(gid >> 5);
    int j = (int)(gid & 31);
    if (e >= e_cnt) return;
    int s = src[e], d = dst[e];
    float norm = dinv[s] * dinv[d];
    float v = norm * proj[(size_t)s * DC + j];
    float* o = (j < DOUT) ? (out + (size_t)d * DOUT + j)
                          : (out + (size_t)n * DOUT + (size_t)d * DOUT + (j - DOUT));
    unsafeAtomicAdd(o, v);
}

extern "C" void kernel_launch(void* const* d_in, const int* in_sizes, int n_in,
                              void* d_out, int out_size, void* d_ws, size_t ws_size,
                              hipStream_t stream) {
    const float* x   = (const float*)d_in[0];
    const int*   ei  = (const int*)d_in[1];
    const float* Wmu = (const float*)d_in[2];
    const float* bmu = (const float*)d_in[3];
    const float* Wls = (const float*)d_in[4];
    const float* bls = (const float*)d_in[5];
    float* out = (float*)d_out;

    int n = in_sizes[0] / DIN;       // 100000
    int e_cnt = in_sizes[1] / 2;     // 1600000
    const int* src = ei;
    const int* dst = ei + e_cnt;

    float* deg  = (float*)d_ws;      // [n]  -> becomes dinv after k_proj
    float* proj = deg + n;           // [n*DC]

    k_init_deg<<<(n + 255) / 256, 256, 0, stream>>>(deg, n);
    k_count<<<(e_cnt + 255) / 256, 256, 0, stream>>>(dst, deg, e_cnt);
    k_proj<<<(n + 255) / 256, 256, 0, stream>>>(x, Wmu, bmu, Wls, bls, deg, proj, out, n);

    long long tasks = (long long)e_cnt * DC;
    int blocks = (int)((tasks + 255) / 256);
    k_scatter<<<blocks, 256, 0, stream>>>(src, dst, deg, proj, out, e_cnt, n);
}